// Round 11
// baseline (97.684 us; speedup 1.0000x reference)
//
#include <hip/hip_runtime.h>
#include <cmath>

typedef _Float16 half8 __attribute__((ext_vector_type(8)));
typedef float f32x4 __attribute__((ext_vector_type(4)));

namespace {
constexpr int BB   = 64;
constexpr int TT   = 1002;
constexpr int DD   = 8;
constexpr int HH   = 64;
constexpr int LAGS = 2;
constexpr int NW   = TT - LAGS;          // 1000
constexpr int FIN  = LAGS * DD + 1;      // 17
constexpr int NTOT = BB * NW;            // 64000
constexpr int WPB  = 128;                // windows per block (4 waves x 32)
constexpr int GXB  = (NW + WPB - 1) / WPB;   // 8
constexpr int NPW  = GXB * 4;            // partial slots per (b,d) = 32

// output layout (flat, return order)
constexpr int RES_OFF = 0;
constexpr int LOG_OFF = NTOT * DD;
constexpr int HJ_OFF  = LOG_OFF + BB;

// prepacked A-fragment arrays in d_ws (f16 units).
// A-frag layout per (mt,kc): lane holds A[m][k], m = mt*16 + (lane&15),
// k = kc*32 + (lane>>4)*8 + j, j=0..7  -> [mt][kc][lane][8] contiguous.
constexpr int SZ_A0F = 4 * 1 * 64 * 8;   // fwd L0: A[h][f], K=32 (pad f>=17 -> 0)
constexpr int SZ_AH  = 4 * 2 * 64 * 8;   // 64x64 matrices, K=64
constexpr int SZ_A0T = 2 * 2 * 64 * 8;   // g-step: A[f][h], M=32 (pad f>=17 -> 0)
constexpr int OA0F = 0;
constexpr int OA1F = OA0F + DD * SZ_A0F; // W1 fwd
constexpr int OA2F = OA1F + DD * SZ_AH;  // W2 fwd
constexpr int OA2T = OA2F + DD * SZ_AH;  // W2^T (v1 step)
constexpr int OA1T = OA2T + DD * SZ_AH;  // W1^T (v0 step)
constexpr int OA0T = OA1T + DD * SZ_AH;  // W0^T (g step)
constexpr int WTOT = OA0T + DD * SZ_A0T; // 163840 f16 = 320 KB
}

// packed f32->f16 conversion (v_cvt_pkrtz_f16_f32): 1 inst / 2 elements.
__device__ __forceinline__ unsigned int pku(float a, float b) {
    return __builtin_bit_cast(unsigned int, __builtin_amdgcn_cvt_pkrtz(a, b));
}

// Prepack all weights into per-lane MFMA A-fragments (f16).
__global__ void setup_weights(const float* __restrict__ W0, const float* __restrict__ W1,
                              const float* __restrict__ W2, _Float16* __restrict__ wsp)
{
    for (int i = blockIdx.x * blockDim.x + threadIdx.x; i < WTOT;
         i += gridDim.x * blockDim.x) {
        float val;
        if (i < OA1F) {          // A0F: A[m=h][k=f] = W0[d,m,k], K=32 padded
            int j = i - OA0F, d = j / SZ_A0F, r = j % SZ_A0F;
            int mt = r / 512, r2 = r % 512, lane = r2 / 8, jj = r2 % 8;
            int m = mt * 16 + (lane & 15), k = (lane >> 4) * 8 + jj;
            val = (k < FIN) ? W0[((size_t)d * HH + m) * FIN + k] : 0.0f;
        } else if (i < OA2F) {   // A1F: A[m][k] = W1[d,m,k]
            int j = i - OA1F, d = j / SZ_AH, r = j % SZ_AH;
            int mt = r / 1024, r2 = r % 1024, kc = r2 / 512, r3 = r2 % 512;
            int lane = r3 / 8, jj = r3 % 8;
            int m = mt * 16 + (lane & 15), k = kc * 32 + (lane >> 4) * 8 + jj;
            val = W1[((size_t)d * HH + m) * HH + k];
        } else if (i < OA2T) {   // A2F: A[m][k] = W2[d,m,k]
            int j = i - OA2F, d = j / SZ_AH, r = j % SZ_AH;
            int mt = r / 1024, r2 = r % 1024, kc = r2 / 512, r3 = r2 % 512;
            int lane = r3 / 8, jj = r3 % 8;
            int m = mt * 16 + (lane & 15), k = kc * 32 + (lane >> 4) * 8 + jj;
            val = W2[((size_t)d * HH + m) * HH + k];
        } else if (i < OA1T) {   // A2T: A[m=h'][k=g] = W2[d,k,m]
            int j = i - OA2T, d = j / SZ_AH, r = j % SZ_AH;
            int mt = r / 1024, r2 = r % 1024, kc = r2 / 512, r3 = r2 % 512;
            int lane = r3 / 8, jj = r3 % 8;
            int m = mt * 16 + (lane & 15), k = kc * 32 + (lane >> 4) * 8 + jj;
            val = W2[((size_t)d * HH + k) * HH + m];
        } else if (i < OA0T) {   // A1T: A[m=h][k=h'] = W1[d,k,m]
            int j = i - OA1T, d = j / SZ_AH, r = j % SZ_AH;
            int mt = r / 1024, r2 = r % 1024, kc = r2 / 512, r3 = r2 % 512;
            int lane = r3 / 8, jj = r3 % 8;
            int m = mt * 16 + (lane & 15), k = kc * 32 + (lane >> 4) * 8 + jj;
            val = W1[((size_t)d * HH + k) * HH + m];
        } else {                 // A0T: A[m=f][k=h] = W0[d,k,m], M=32 padded
            int j = i - OA0T, d = j / SZ_A0T, r = j % SZ_A0T;
            int mt = r / 1024, r2 = r % 1024, kc = r2 / 512, r3 = r2 % 512;
            int lane = r3 / 8, jj = r3 % 8;
            int m = mt * 16 + (lane & 15), k = kc * 32 + (lane >> 4) * 8 + jj;
            val = (m < FIN) ? W0[((size_t)d * HH + k) * FIN + m] : 0.0f;
        }
        wsp[i] = (_Float16)val;
    }
}

// swizzled LDS byte address for activation rows (128B each):
// XOR bits 4-6 with (n&7) -> conflict-light reads and writes.
__device__ __forceinline__ int swb(int n, int byteoff) {
    return n * 128 + (byteoff ^ ((n & 7) << 4));
}

// Dual-chain waves: block = (128-window tile, b, d), 256 threads = 4 waves.
// Each wave owns TWO independent 16-window strips processed as interleaved
// dependency chains (C0/C1); A-fragments loaded once per stage and shared by
// both chains. No LDS fences anywhere: same-wave DS ops execute in order
// (RAW through LDS is HW-ordered; lgkmcnt only gates register availability),
// and the round-9/10 wave-wide lgkmcnt(0) fences were serializing the chains.
// launch_bounds(256,4): 4 blocks/CU semantics (rounds 5/6 calibration) ->
// 16 waves/CU -> 128-VGPR budget for the ~110-reg dual-chain live set.
__global__ __launch_bounds__(256, 4) void fused_mlp(
    const float* __restrict__ x,
    const float* __restrict__ b0, const float* __restrict__ a0,
    const float* __restrict__ b1, const float* __restrict__ a1,
    const float* __restrict__ b2, const float* __restrict__ a2,
    const float* __restrict__ W3, const float* __restrict__ b3,
    const _Float16* __restrict__ wsp,
    float* __restrict__ out, float* __restrict__ partials)
{
    const int b   = blockIdx.y;    // 0..BB-1
    const int d   = blockIdx.z;    // 0..DD-1
    const int tid = threadIdx.x;
    const int wv  = __builtin_amdgcn_readfirstlane(tid >> 6);  // 0..3
    const int t   = tid & 63;
    const int hi  = t >> 4, lo = t & 15;
    const int wbase = blockIdx.x * WPB + wv * 32;   // wave's 32-window base

    __shared__ __align__(16) unsigned char Xs[128 * 128];  // 16KB, 4KB/wave

    const int r0 = wv * 32 + lo;        // strip0 LDS row
    const int r1 = r0 + 16;             // strip1 LDS row
    const int n0 = wbase + lo;          // strip0 window
    const int n1 = n0 + 16;             // strip1 window
    const bool nv0 = (n0 < NW), nv1 = (n1 < NW);

    // B-frag read addresses (loop-invariant)
    const int rd00 = swb(r0, hi * 16), rd01 = swb(r0, 64 + hi * 16);
    const int rd10 = swb(r1, hi * 16), rd11 = swb(r1, 64 + hi * 16);

    // ---- stage both strips: lanes hi<2 each load one window row ----
    if (hi < 2) {
        const int nr = wv * 32 + hi * 16 + lo;
        const int w  = min(wbase + hi * 16 + lo, NW - 1);
        const float* xr = x + ((size_t)b * TT + w) * DD;
        f32x4 x0 = *(const f32x4*)(xr + 0);
        f32x4 x1 = *(const f32x4*)(xr + 4);
        f32x4 x2 = *(const f32x4*)(xr + 8);
        f32x4 x3 = *(const f32x4*)(xr + 12);
        float xl = xr[2 * DD + d];
        uint4 q0, q1, qz, zz;
        q0.x = pku(x0[0], x0[1]); q0.y = pku(x0[2], x0[3]);
        q0.z = pku(x1[0], x1[1]); q0.w = pku(x1[2], x1[3]);
        q1.x = pku(x2[0], x2[1]); q1.y = pku(x2[2], x2[3]);
        q1.z = pku(x3[0], x3[1]); q1.w = pku(x3[2], x3[3]);
        qz.x = pku(xl, 0.f); qz.y = 0u; qz.z = 0u; qz.w = 0u;
        zz.x = 0u; zz.y = 0u; zz.z = 0u; zz.w = 0u;
        *(uint4*)&Xs[swb(nr, 0)]  = q0;
        *(uint4*)&Xs[swb(nr, 16)] = q1;
        *(uint4*)&Xs[swb(nr, 32)] = qz;
        *(uint4*)&Xs[swb(nr, 48)] = zz;
    }
    // no fence: in-order DS pipe orders the reads below behind these writes

    const float A0v = a0[d], A1v = a1[d], A2v = a2[d];
    f32x4 C0[4], C1[4];   // [mt]: row h = mt*16 + hi*4 + r; col = lo

    // dual-chain K=64 GEMM: A loaded once, both strips' B/MFMA interleaved
    auto gemm2 = [&](const _Float16* apk, const float* bias) {
        half8 A[8];
        #pragma unroll
        for (int q = 0; q < 8; ++q)
            A[q] = *(const half8*)(apk + (size_t)(q * 64 + t) * 8);
        half8 B00 = *(const half8*)&Xs[rd00];
        half8 B01 = *(const half8*)&Xs[rd01];
        half8 B10 = *(const half8*)&Xs[rd10];
        half8 B11 = *(const half8*)&Xs[rd11];
        if (bias) {
            #pragma unroll
            for (int mt = 0; mt < 4; ++mt) {
                f32x4 bb = *(const f32x4*)(bias + mt * 16 + hi * 4);
                C0[mt] = bb; C1[mt] = bb;
            }
        } else {
            #pragma unroll
            for (int mt = 0; mt < 4; ++mt) {
                C0[mt][0]=0.f;C0[mt][1]=0.f;C0[mt][2]=0.f;C0[mt][3]=0.f;
                C1[mt][0]=0.f;C1[mt][1]=0.f;C1[mt][2]=0.f;C1[mt][3]=0.f;
            }
        }
        #pragma unroll
        for (int mt = 0; mt < 4; ++mt) {
            C0[mt] = __builtin_amdgcn_mfma_f32_16x16x32_f16(A[2*mt],   B00, C0[mt], 0,0,0);
            C1[mt] = __builtin_amdgcn_mfma_f32_16x16x32_f16(A[2*mt],   B10, C1[mt], 0,0,0);
            C0[mt] = __builtin_amdgcn_mfma_f32_16x16x32_f16(A[2*mt+1], B01, C0[mt], 0,0,0);
            C1[mt] = __builtin_amdgcn_mfma_f32_16x16x32_f16(A[2*mt+1], B11, C1[mt], 0,0,0);
        }
    };

    // store both chains' C (f16) into their private rows
    auto storeC2 = [&]() {
        #pragma unroll
        for (int mt = 0; mt < 4; ++mt) {
            uint2 p0, p1;
            p0.x = pku(C0[mt][0], C0[mt][1]); p0.y = pku(C0[mt][2], C0[mt][3]);
            p1.x = pku(C1[mt][0], C1[mt][1]); p1.y = pku(C1[mt][2], C1[mt][3]);
            *(uint2*)&Xs[swb(r0, mt * 32 + hi * 8)] = p0;
            *(uint2*)&Xs[swb(r1, mt * 32 + hi * 8)] = p1;
        }
    };

    unsigned int m0a=0u, m1a=0u, m2a=0u, m0b=0u, m1b=0u, m2b=0u; // bit = mt*4+r
    auto prelu = [&](f32x4* C, float slope, unsigned int& mask) {
        #pragma unroll
        for (int mt = 0; mt < 4; ++mt)
            #pragma unroll
            for (int r = 0; r < 4; ++r) {
                float z = C[mt][r];
                if (z > 0.0f) mask |= 1u << (mt * 4 + r);
                C[mt][r] = fmaxf(z, slope * z);  // slope=0.25 in [0,1]
            }
    };
    auto bwd_mask = [&](f32x4* C, float slope, unsigned int mask) {
        #pragma unroll
        for (int mt = 0; mt < 4; ++mt)
            #pragma unroll
            for (int r = 0; r < 4; ++r)
                if (!((mask >> (mt * 4 + r)) & 1u))
                    C[mt][r] *= slope;
    };

    // ================= forward =================
    // layer 0: K=32, A0F layout [mt][lane][8]
    {
        const _Float16* apk = wsp + OA0F + (size_t)d * SZ_A0F;
        half8 A[4];
        #pragma unroll
        for (int q = 0; q < 4; ++q)
            A[q] = *(const half8*)(apk + (size_t)(q * 64 + t) * 8);
        half8 B00 = *(const half8*)&Xs[rd00];
        half8 B10 = *(const half8*)&Xs[rd10];
        #pragma unroll
        for (int mt = 0; mt < 4; ++mt) {
            f32x4 bb = *(const f32x4*)(b0 + d * HH + mt * 16 + hi * 4);
            C0[mt] = bb; C1[mt] = bb;
        }
        #pragma unroll
        for (int mt = 0; mt < 4; ++mt) {
            C0[mt] = __builtin_amdgcn_mfma_f32_16x16x32_f16(A[mt], B00, C0[mt], 0,0,0);
            C1[mt] = __builtin_amdgcn_mfma_f32_16x16x32_f16(A[mt], B10, C1[mt], 0,0,0);
        }
    }
    prelu(C0, A0v, m0a); prelu(C1, A0v, m0b); storeC2();

    gemm2(wsp + OA1F + (size_t)d * SZ_AH, b1 + d * HH);
    prelu(C0, A1v, m1a); prelu(C1, A1v, m1b); storeC2();

    gemm2(wsp + OA2F + (size_t)d * SZ_AH, b2 + d * HH);
    prelu(C0, A2v, m2a); prelu(C1, A2v, m2b);

    // ---- output dot (full h per window in this wave) ----
    f32x4 w3v[4];
    #pragma unroll
    for (int mt = 0; mt < 4; ++mt)
        w3v[mt] = *(const f32x4*)(W3 + d * HH + mt * 16 + hi * 4);
    {
        float s0 = 0.f, s1 = 0.f;
        #pragma unroll
        for (int mt = 0; mt < 4; ++mt)
            #pragma unroll
            for (int r = 0; r < 4; ++r) {
                s0 = fmaf(w3v[mt][r], C0[mt][r], s0);
                s1 = fmaf(w3v[mt][r], C1[mt][r], s1);
            }
        s0 += __shfl_xor(s0, 16); s0 += __shfl_xor(s0, 32);
        s1 += __shfl_xor(s1, 16); s1 += __shfl_xor(s1, 32);
        if (hi == 0) {
            const float b3v = b3[d];
            if (nv0) out[RES_OFF + ((size_t)b * NW + n0) * DD + d] = s0 + b3v;
            if (nv1) out[RES_OFF + ((size_t)b * NW + n1) * DD + d] = s1 + b3v;
        }
    }

    // ================= backward =================
    #pragma unroll
    for (int mt = 0; mt < 4; ++mt)
        #pragma unroll
        for (int r = 0; r < 4; ++r) {
            float d0v = ((m2a >> (mt * 4 + r)) & 1u) ? 1.0f : A2v;
            float d1v = ((m2b >> (mt * 4 + r)) & 1u) ? 1.0f : A2v;
            C0[mt][r] = w3v[mt][r] * d0v;
            C1[mt][r] = w3v[mt][r] * d1v;
        }
    storeC2();

    gemm2(wsp + OA2T + (size_t)d * SZ_AH, nullptr);
    bwd_mask(C0, A1v, m1a); bwd_mask(C1, A1v, m1b); storeC2();

    gemm2(wsp + OA1T + (size_t)d * SZ_AH, nullptr);
    bwd_mask(C0, A0v, m0a); bwd_mask(C1, A0v, m0b); storeC2();

    // ---- g = W0^T @ v0 : M=32 (f rows), both strips ----
    f32x4 G0[2], G1[2];
    {
        const _Float16* apk = wsp + OA0T + (size_t)d * SZ_A0T;
        half8 A[4];
        #pragma unroll
        for (int q = 0; q < 4; ++q)
            A[q] = *(const half8*)(apk + (size_t)(q * 64 + t) * 8);
        half8 B00 = *(const half8*)&Xs[rd00];
        half8 B01 = *(const half8*)&Xs[rd01];
        half8 B10 = *(const half8*)&Xs[rd10];
        half8 B11 = *(const half8*)&Xs[rd11];
        #pragma unroll
        for (int mt = 0; mt < 2; ++mt) {
            G0[mt][0]=0.f;G0[mt][1]=0.f;G0[mt][2]=0.f;G0[mt][3]=0.f;
            G1[mt][0]=0.f;G1[mt][1]=0.f;G1[mt][2]=0.f;G1[mt][3]=0.f;
            G0[mt] = __builtin_amdgcn_mfma_f32_16x16x32_f16(A[2*mt],   B00, G0[mt], 0,0,0);
            G1[mt] = __builtin_amdgcn_mfma_f32_16x16x32_f16(A[2*mt],   B10, G1[mt], 0,0,0);
            G0[mt] = __builtin_amdgcn_mfma_f32_16x16x32_f16(A[2*mt+1], B01, G0[mt], 0,0,0);
            G1[mt] = __builtin_amdgcn_mfma_f32_16x16x32_f16(A[2*mt+1], B11, G1[mt], 0,0,0);
        }
    }

    // hist_jac: f = hi*4 + r (G[0] rows 0..15), n = lane's window
    if (nv0)
        *(f32x4*)(out + HJ_OFF + ((size_t)d * NTOT + (size_t)b * NW + n0) * 16
                  + hi * 4) = G0[0];
    if (nv1)
        *(f32x4*)(out + HJ_OFF + ((size_t)d * NTOT + (size_t)b * NW + n1) * 16
                  + hi * 4) = G1[0];

    // log|g[16]|: f=16 -> G[1] reg 0 on hi==0 lanes
    {
        float ld = 0.0f;
        if (hi == 0) {
            if (nv0) ld += __logf(fabsf(G0[1][0]));
            if (nv1) ld += __logf(fabsf(G1[1][0]));
        }
        #pragma unroll
        for (int off = 32; off > 0; off >>= 1) ld += __shfl_down(ld, off);
        if (t == 0) partials[(b * DD + d) * NPW + blockIdx.x * 4 + wv] = ld;
    }
}

__global__ void reduce_log(const float* __restrict__ partials, float* __restrict__ out)
{
    const int b = threadIdx.x;   // 64 threads
    float s = 0.0f;
    #pragma unroll 16
    for (int i = 0; i < DD * NPW; ++i) s += partials[b * (DD * NPW) + i];
    out[LOG_OFF + b] = s;
}

extern "C" void kernel_launch(void* const* d_in, const int* in_sizes, int n_in,
                              void* d_out, int out_size, void* d_ws, size_t ws_size,
                              hipStream_t stream)
{
    const float* x  = (const float*)d_in[0];
    const float* W0 = (const float*)d_in[1];
    const float* b0 = (const float*)d_in[2];
    const float* a0 = (const float*)d_in[3];
    const float* W1 = (const float*)d_in[4];
    const float* b1 = (const float*)d_in[5];
    const float* a1 = (const float*)d_in[6];
    const float* W2 = (const float*)d_in[7];
    const float* b2 = (const float*)d_in[8];
    const float* a2 = (const float*)d_in[9];
    const float* W3 = (const float*)d_in[10];
    const float* b3 = (const float*)d_in[11];

    float*     out      = (float*)d_out;
    _Float16*  wsp      = (_Float16*)d_ws;
    float*     partials = (float*)((char*)d_ws + (size_t)WTOT * 2);  // 16384 floats

    setup_weights<<<160, 1024, 0, stream>>>(W0, W1, W2, wsp);

    dim3 grid(GXB, BB, DD);   // 8 x 64 x 8 = 4096 blocks x 4 dual-chain waves
    fused_mlp<<<grid, 256, 0, stream>>>(x, b0, a0, b1, a1, b2, a2, W3, b3,
                                        wsp, out, partials);
    reduce_log<<<1, BB, 0, stream>>>(partials, out);
}

// Round 12
// 83.134 us; speedup vs baseline: 1.1750x; 1.1750x over previous
//
#include <hip/hip_runtime.h>
#include <cmath>

typedef _Float16 half8 __attribute__((ext_vector_type(8)));
typedef _Float16 h2t   __attribute__((ext_vector_type(2)));
typedef float f32x4 __attribute__((ext_vector_type(4)));

namespace {
constexpr int BB   = 64;
constexpr int TT   = 1002;
constexpr int DD   = 8;
constexpr int HH   = 64;
constexpr int LAGS = 2;
constexpr int NW   = TT - LAGS;          // 1000
constexpr int FIN  = LAGS * DD + 1;      // 17
constexpr int NTOT = BB * NW;            // 64000
constexpr int GXB  = 16;                 // x-blocks (64 windows each)
constexpr int NSTR = GXB * 4;            // 64 strips of 16 windows per (b,d)

// output layout (flat, return order)
constexpr int RES_OFF = 0;
constexpr int LOG_OFF = NTOT * DD;
constexpr int HJ_OFF  = LOG_OFF + BB;

// prepacked A-fragment arrays in d_ws (f16 units); layout as rounds 4-11.
constexpr int SZ_A0F = 4 * 1 * 64 * 8;
constexpr int SZ_AH  = 4 * 2 * 64 * 8;
constexpr int SZ_A0T = 2 * 2 * 64 * 8;
constexpr int OA0F = 0;
constexpr int OA1F = OA0F + DD * SZ_A0F;
constexpr int OA2F = OA1F + DD * SZ_AH;
constexpr int OA2T = OA2F + DD * SZ_AH;
constexpr int OA1T = OA2T + DD * SZ_AH;
constexpr int OA0T = OA1T + DD * SZ_AH;
constexpr int WTOT = OA0T + DD * SZ_A0T; // 163840 f16 = 320 KB

// LDS regions (byte offsets; fold into ds-instruction immediates)
constexpr int REG_H0 = 8192;
constexpr int REG_H1 = 16384;
}

__device__ __forceinline__ unsigned int pku(float a, float b) {
    return __builtin_bit_cast(unsigned int, __builtin_amdgcn_cvt_pkrtz(a, b));
}
__device__ __forceinline__ h2t pmax(h2t a, h2t b) {
#if __has_builtin(__builtin_elementwise_max)
    return __builtin_elementwise_max(a, b);   // v_pk_max_f16
#else
    h2t r; r[0] = a[0] > b[0] ? a[0] : b[0]; r[1] = a[1] > b[1] ? a[1] : b[1];
    return r;
#endif
}
__device__ __forceinline__ float fdot2(h2t a, h2t b, float c) {
#if __has_builtin(__builtin_amdgcn_fdot2)
    return __builtin_amdgcn_fdot2(a, b, c, false);
#else
    return c + (float)a[0] * (float)b[0] + (float)a[1] * (float)b[1];
#endif
}

// Prepack all weights into per-lane MFMA A-fragments (f16). Unchanged.
__global__ void setup_weights(const float* __restrict__ W0, const float* __restrict__ W1,
                              const float* __restrict__ W2, _Float16* __restrict__ wsp)
{
    for (int i = blockIdx.x * blockDim.x + threadIdx.x; i < WTOT;
         i += gridDim.x * blockDim.x) {
        float val;
        if (i < OA1F) {
            int j = i - OA0F, d = j / SZ_A0F, r = j % SZ_A0F;
            int mt = r / 512, r2 = r % 512, lane = r2 / 8, jj = r2 % 8;
            int m = mt * 16 + (lane & 15), k = (lane >> 4) * 8 + jj;
            val = (k < FIN) ? W0[((size_t)d * HH + m) * FIN + k] : 0.0f;
        } else if (i < OA2F) {
            int j = i - OA1F, d = j / SZ_AH, r = j % SZ_AH;
            int mt = r / 1024, r2 = r % 1024, kc = r2 / 512, r3 = r2 % 512;
            int lane = r3 / 8, jj = r3 % 8;
            int m = mt * 16 + (lane & 15), k = kc * 32 + (lane >> 4) * 8 + jj;
            val = W1[((size_t)d * HH + m) * HH + k];
        } else if (i < OA2T) {
            int j = i - OA2F, d = j / SZ_AH, r = j % SZ_AH;
            int mt = r / 1024, r2 = r % 1024, kc = r2 / 512, r3 = r2 % 512;
            int lane = r3 / 8, jj = r3 % 8;
            int m = mt * 16 + (lane & 15), k = kc * 32 + (lane >> 4) * 8 + jj;
            val = W2[((size_t)d * HH + m) * HH + k];
        } else if (i < OA1T) {
            int j = i - OA2T, d = j / SZ_AH, r = j % SZ_AH;
            int mt = r / 1024, r2 = r % 1024, kc = r2 / 512, r3 = r2 % 512;
            int lane = r3 / 8, jj = r3 % 8;
            int m = mt * 16 + (lane & 15), k = kc * 32 + (lane >> 4) * 8 + jj;
            val = W2[((size_t)d * HH + k) * HH + m];
        } else if (i < OA0T) {
            int j = i - OA1T, d = j / SZ_AH, r = j % SZ_AH;
            int mt = r / 1024, r2 = r % 1024, kc = r2 / 512, r3 = r2 % 512;
            int lane = r3 / 8, jj = r3 % 8;
            int m = mt * 16 + (lane & 15), k = kc * 32 + (lane >> 4) * 8 + jj;
            val = W1[((size_t)d * HH + k) * HH + m];
        } else {
            int j = i - OA0T, d = j / SZ_A0T, r = j % SZ_A0T;
            int mt = r / 1024, r2 = r % 1024, kc = r2 / 512, r3 = r2 % 512;
            int lane = r3 / 8, jj = r3 % 8;
            int m = mt * 16 + (lane & 15), k = kc * 32 + (lane >> 4) * 8 + jj;
            val = (m < FIN) ? W0[((size_t)d * HH + k) * FIN + m] : 0.0f;
        }
        wsp[i] = (_Float16)val;
    }
}

// swizzled LDS byte address (rows 128B): XOR bits 4-6 with (row&7).
// Region offsets (+8192/+16384) preserve the swizzle ((row+64)&7 == row&7).
__device__ __forceinline__ int swb(int n, int byteoff) {
    return n * 128 + (byteoff ^ ((n & 7) << 4));
}

// Round-12: round-9/10 N-split barrier-free structure + minimal-VALU epilogues.
// Per wave: 16 windows, full M=64. Forward h' tiles kept in H0/H1 LDS regions;
// backward derives the PReLU derivative from the SIGN BIT of stored h'
// (sign(h')==sign(z); pkrtz preserves -0) -> no mask registers, no bit tests.
// PReLU done packed-f16 post-cvt: pk_mul + pk_max (a=0.25 in [0,1]).
__global__ __launch_bounds__(256) void fused_mlp(
    const float* __restrict__ x,
    const float* __restrict__ b0, const float* __restrict__ a0,
    const float* __restrict__ b1, const float* __restrict__ a1,
    const float* __restrict__ b2, const float* __restrict__ a2,
    const float* __restrict__ W3, const float* __restrict__ b3,
    const _Float16* __restrict__ wsp,
    float* __restrict__ out, float* __restrict__ partials)
{
    const int b   = blockIdx.y;
    const int d   = blockIdx.z;
    const int tid = threadIdx.x;
    const int wv  = __builtin_amdgcn_readfirstlane(tid >> 6);  // 0..3
    const int t   = tid & 63;
    const int hi  = t >> 4, lo = t & 15;
    const int w0s = blockIdx.x * 64 + wv * 16;
    const int n   = w0s + lo;
    const bool nv = (n < NW);
    const int row = wv * 16 + lo;               // private row in each region

    __shared__ __align__(16) unsigned char Xs[192 * 128];  // 24KB: work|h0|h1

    const int rd0 = swb(row, hi * 16);          // B-frag kc0 (work region)
    const int rd1 = swb(row, 64 + hi * 16);     // B-frag kc1
    int wr[4];
    #pragma unroll
    for (int mt = 0; mt < 4; ++mt) wr[mt] = swb(row, mt * 32 + hi * 8);

    // ---- stage inputs into WORK rows (hi==0 lanes) ----
    if (hi == 0) {
        const int w = min(w0s + lo, NW - 1);
        const float* xr = x + ((size_t)b * TT + w) * DD;
        f32x4 x0 = *(const f32x4*)(xr + 0);
        f32x4 x1 = *(const f32x4*)(xr + 4);
        f32x4 x2 = *(const f32x4*)(xr + 8);
        f32x4 x3 = *(const f32x4*)(xr + 12);
        float xl = xr[2 * DD + d];
        uint4 q0, q1, qz, zz;
        q0.x = pku(x0[0], x0[1]); q0.y = pku(x0[2], x0[3]);
        q0.z = pku(x1[0], x1[1]); q0.w = pku(x1[2], x1[3]);
        q1.x = pku(x2[0], x2[1]); q1.y = pku(x2[2], x2[3]);
        q1.z = pku(x3[0], x3[1]); q1.w = pku(x3[2], x3[3]);
        qz.x = pku(xl, 0.f); qz.y = 0u; qz.z = 0u; qz.w = 0u;
        zz.x = 0u; zz.y = 0u; zz.z = 0u; zz.w = 0u;
        *(uint4*)&Xs[swb(row, 0)]  = q0;
        *(uint4*)&Xs[swb(row, 16)] = q1;
        *(uint4*)&Xs[swb(row, 32)] = qz;
        *(uint4*)&Xs[swb(row, 48)] = zz;
    }
    // no fence: same-wave DS ops are in-order; compiler inserts lgkmcnt waits

    const float A0f = a0[d], A1f = a1[d], A2f = a2[d];
    const h2t apk0 = __builtin_bit_cast(h2t, pku(A0f, A0f));
    const h2t apk1 = __builtin_bit_cast(h2t, pku(A1f, A1f));
    const h2t apk2 = __builtin_bit_cast(h2t, pku(A2f, A2f));

    f32x4 C[4];

    // K=64 GEMM over full M=64; B from work-region private rows
    auto gemmK64 = [&](const _Float16* apk) {
        half8 B0 = *(const half8*)&Xs[rd0];
        half8 B1 = *(const half8*)&Xs[rd1];
        #pragma unroll
        for (int mt = 0; mt < 4; ++mt) {
            half8 a0f = *(const half8*)(apk + (size_t)((mt * 2 + 0) * 64 + t) * 8);
            C[mt] = __builtin_amdgcn_mfma_f32_16x16x32_f16(a0f, B0, C[mt], 0, 0, 0);
            half8 a1f = *(const half8*)(apk + (size_t)((mt * 2 + 1) * 64 + t) * 8);
            C[mt] = __builtin_amdgcn_mfma_f32_16x16x32_f16(a1f, B1, C[mt], 0, 0, 0);
        }
    };

    // packed PReLU + store to region (cvt -> pk_mul -> pk_max -> ds_write_b64)
    auto preluStore = [&](h2t apk, int regoff) {
        #pragma unroll
        for (int mt = 0; mt < 4; ++mt) {
            unsigned ux = pku(C[mt][0], C[mt][1]);
            unsigned uy = pku(C[mt][2], C[mt][3]);
            h2t hx = __builtin_bit_cast(h2t, ux);
            h2t hy = __builtin_bit_cast(h2t, uy);
            h2t rx = pmax(hx, hx * apk);
            h2t ry = pmax(hy, hy * apk);
            uint2 p;
            p.x = __builtin_bit_cast(unsigned int, rx);
            p.y = __builtin_bit_cast(unsigned int, ry);
            *(uint2*)&Xs[wr[mt] + regoff] = p;
        }
    };

    // backward: v' = v * d, d from sign of stored h' (hr); store to WORK
    auto dApplyStore = [&](h2t apk, const uint2* hr) {
        #pragma unroll
        for (int mt = 0; mt < 4; ++mt) {
            unsigned vx = pku(C[mt][0], C[mt][1]);
            unsigned vy = pku(C[mt][2], C[mt][3]);
            unsigned avx = __builtin_bit_cast(unsigned int,
                               __builtin_bit_cast(h2t, vx) * apk);
            unsigned avy = __builtin_bit_cast(unsigned int,
                               __builtin_bit_cast(h2t, vy) * apk);
            unsigned mx = ((hr[mt].x & 0x80008000u) >> 15) * 0xFFFFu;
            unsigned my = ((hr[mt].y & 0x80008000u) >> 15) * 0xFFFFu;
            uint2 p;
            p.x = (mx & avx) | (~mx & vx);
            p.y = (my & avy) | (~my & vy);
            *(uint2*)&Xs[wr[mt]] = p;
        }
    };

    // ================= forward =================
    // L0: K=32, bias as C-in
    {
        const _Float16* apk = wsp + OA0F + (size_t)d * SZ_A0F;
        #pragma unroll
        for (int mt = 0; mt < 4; ++mt)
            C[mt] = *(const f32x4*)(b0 + d * HH + mt * 16 + hi * 4);
        half8 B0 = *(const half8*)&Xs[rd0];
        #pragma unroll
        for (int mt = 0; mt < 4; ++mt) {
            half8 a = *(const half8*)(apk + (size_t)(mt * 64 + t) * 8);
            C[mt] = __builtin_amdgcn_mfma_f32_16x16x32_f16(a, B0, C[mt], 0, 0, 0);
        }
    }
    preluStore(apk0, REG_H0);

    // L1: B from H0
    {
        const _Float16* apk = wsp + OA1F + (size_t)d * SZ_AH;
        #pragma unroll
        for (int mt = 0; mt < 4; ++mt)
            C[mt] = *(const f32x4*)(b1 + d * HH + mt * 16 + hi * 4);
        half8 B0 = *(const half8*)&Xs[rd0 + REG_H0];
        half8 B1 = *(const half8*)&Xs[rd1 + REG_H0];
        #pragma unroll
        for (int mt = 0; mt < 4; ++mt) {
            half8 a0f = *(const half8*)(apk + (size_t)((mt * 2 + 0) * 64 + t) * 8);
            C[mt] = __builtin_amdgcn_mfma_f32_16x16x32_f16(a0f, B0, C[mt], 0, 0, 0);
            half8 a1f = *(const half8*)(apk + (size_t)((mt * 2 + 1) * 64 + t) * 8);
            C[mt] = __builtin_amdgcn_mfma_f32_16x16x32_f16(a1f, B1, C[mt], 0, 0, 0);
        }
    }
    preluStore(apk1, REG_H1);

    // L2: B from H1
    {
        const _Float16* apk = wsp + OA2F + (size_t)d * SZ_AH;
        #pragma unroll
        for (int mt = 0; mt < 4; ++mt)
            C[mt] = *(const f32x4*)(b2 + d * HH + mt * 16 + hi * 4);
        half8 B0 = *(const half8*)&Xs[rd0 + REG_H1];
        half8 B1 = *(const half8*)&Xs[rd1 + REG_H1];
        #pragma unroll
        for (int mt = 0; mt < 4; ++mt) {
            half8 a0f = *(const half8*)(apk + (size_t)((mt * 2 + 0) * 64 + t) * 8);
            C[mt] = __builtin_amdgcn_mfma_f32_16x16x32_f16(a0f, B0, C[mt], 0, 0, 0);
            half8 a1f = *(const half8*)(apk + (size_t)((mt * 2 + 1) * 64 + t) * 8);
            C[mt] = __builtin_amdgcn_mfma_f32_16x16x32_f16(a1f, B1, C[mt], 0, 0, 0);
        }
    }

    // ---- h2 packed (prelu applied packed), residual dot via fdot2, v2 init ----
    {
        // w3 packed per mt
        uint2 w3p[4];
        #pragma unroll
        for (int mt = 0; mt < 4; ++mt) {
            f32x4 w = *(const f32x4*)(W3 + d * HH + mt * 16 + hi * 4);
            w3p[mt].x = pku(w[0], w[1]);
            w3p[mt].y = pku(w[2], w[3]);
        }
        float s = 0.0f;
        uint2 h2p[4];
        #pragma unroll
        for (int mt = 0; mt < 4; ++mt) {
            unsigned ux = pku(C[mt][0], C[mt][1]);
            unsigned uy = pku(C[mt][2], C[mt][3]);
            h2t hx = __builtin_bit_cast(h2t, ux);
            h2t hy = __builtin_bit_cast(h2t, uy);
            h2t rx = pmax(hx, hx * apk2);
            h2t ry = pmax(hy, hy * apk2);
            h2p[mt].x = __builtin_bit_cast(unsigned int, rx);
            h2p[mt].y = __builtin_bit_cast(unsigned int, ry);
            s = fdot2(rx, __builtin_bit_cast(h2t, w3p[mt].x), s);
            s = fdot2(ry, __builtin_bit_cast(h2t, w3p[mt].y), s);
        }
        s += __shfl_xor(s, 16);
        s += __shfl_xor(s, 32);
        if (hi == 0 && nv)
            out[RES_OFF + ((size_t)b * NW + n) * DD + d] = s + b3[d];

        // v2 = w3 * d2 (d2 from sign of h2) -> WORK
        #pragma unroll
        for (int mt = 0; mt < 4; ++mt) {
            unsigned wax = __builtin_bit_cast(unsigned int,
                              __builtin_bit_cast(h2t, w3p[mt].x) * apk2);
            unsigned way = __builtin_bit_cast(unsigned int,
                              __builtin_bit_cast(h2t, w3p[mt].y) * apk2);
            unsigned mx = ((h2p[mt].x & 0x80008000u) >> 15) * 0xFFFFu;
            unsigned my = ((h2p[mt].y & 0x80008000u) >> 15) * 0xFFFFu;
            uint2 p;
            p.x = (mx & wax) | (~mx & w3p[mt].x);
            p.y = (my & way) | (~my & w3p[mt].y);
            *(uint2*)&Xs[wr[mt]] = p;
        }
    }

    // ================= backward =================
    const f32x4 z4 = {0.f, 0.f, 0.f, 0.f};

    // T2: v1 = (v2 @ W2T) * d1   (d1 from H1 sign; reads issued early)
    {
        uint2 hr[4];
        #pragma unroll
        for (int mt = 0; mt < 4; ++mt) hr[mt] = *(const uint2*)&Xs[wr[mt] + REG_H1];
        #pragma unroll
        for (int mt = 0; mt < 4; ++mt) C[mt] = z4;
        gemmK64(wsp + OA2T + (size_t)d * SZ_AH);
        dApplyStore(apk1, hr);
    }

    // T1: v0 = (v1 @ W1T) * d0   (d0 from H0 sign)
    {
        uint2 hr[4];
        #pragma unroll
        for (int mt = 0; mt < 4; ++mt) hr[mt] = *(const uint2*)&Xs[wr[mt] + REG_H0];
        #pragma unroll
        for (int mt = 0; mt < 4; ++mt) C[mt] = z4;
        gemmK64(wsp + OA1T + (size_t)d * SZ_AH);
        dApplyStore(apk0, hr);
    }

    // G = W0T @ v0 : M=32 (f rows)
    f32x4 G[2];
    {
        const _Float16* apk = wsp + OA0T + (size_t)d * SZ_A0T;
        G[0] = z4; G[1] = z4;
        half8 B0 = *(const half8*)&Xs[rd0];
        half8 B1 = *(const half8*)&Xs[rd1];
        #pragma unroll
        for (int mt = 0; mt < 2; ++mt) {
            half8 a0f = *(const half8*)(apk + (size_t)((mt * 2 + 0) * 64 + t) * 8);
            G[mt] = __builtin_amdgcn_mfma_f32_16x16x32_f16(a0f, B0, G[mt], 0, 0, 0);
            half8 a1f = *(const half8*)(apk + (size_t)((mt * 2 + 1) * 64 + t) * 8);
            G[mt] = __builtin_amdgcn_mfma_f32_16x16x32_f16(a1f, B1, G[mt], 0, 0, 0);
        }
    }

    // hist_jac: f = hi*4 + r (G[0] rows 0..15)
    if (nv)
        *(f32x4*)(out + HJ_OFF + ((size_t)d * NTOT + (size_t)b * NW + n) * 16
                  + hi * 4) = G[0];

    // log|g[16]|: G[1] reg 0 on hi==0 lanes
    {
        float ld = (hi == 0 && nv) ? __logf(fabsf(G[1][0])) : 0.0f;
        #pragma unroll
        for (int off = 32; off > 0; off >>= 1) ld += __shfl_down(ld, off);
        if (t == 0) partials[(b * DD + d) * NSTR + blockIdx.x * 4 + wv] = ld;
    }
}

__global__ void reduce_log(const float* __restrict__ partials, float* __restrict__ out)
{
    const int b = threadIdx.x;   // 64 threads
    float s = 0.0f;
    for (int i = 0; i < DD * NSTR; ++i) s += partials[b * (DD * NSTR) + i];
    out[LOG_OFF + b] = s;
}

extern "C" void kernel_launch(void* const* d_in, const int* in_sizes, int n_in,
                              void* d_out, int out_size, void* d_ws, size_t ws_size,
                              hipStream_t stream)
{
    const float* x  = (const float*)d_in[0];
    const float* W0 = (const float*)d_in[1];
    const float* b0 = (const float*)d_in[2];
    const float* a0 = (const float*)d_in[3];
    const float* W1 = (const float*)d_in[4];
    const float* b1 = (const float*)d_in[5];
    const float* a1 = (const float*)d_in[6];
    const float* W2 = (const float*)d_in[7];
    const float* b2 = (const float*)d_in[8];
    const float* a2 = (const float*)d_in[9];
    const float* W3 = (const float*)d_in[10];
    const float* b3 = (const float*)d_in[11];

    float*     out      = (float*)d_out;
    _Float16*  wsp      = (_Float16*)d_ws;
    float*     partials = (float*)((char*)d_ws + (size_t)WTOT * 2);  // 32768 floats

    setup_weights<<<160, 1024, 0, stream>>>(W0, W1, W2, wsp);

    dim3 grid(GXB, BB, DD);   // 16 x 64 x 8 = 8192 blocks x 4 independent waves
    fused_mlp<<<grid, 256, 0, stream>>>(x, b0, a0, b1, a1, b2, a2, W3, b3,
                                        wsp, out, partials);
    reduce_log<<<1, BB, 0, stream>>>(partials, out);
}

// Round 13
// 61.942 us; speedup vs baseline: 1.5770x; 1.3421x over previous
//
#include <hip/hip_runtime.h>
#include <cmath>

typedef _Float16 half8 __attribute__((ext_vector_type(8)));
typedef _Float16 h2t   __attribute__((ext_vector_type(2)));
typedef float f32x4  __attribute__((ext_vector_type(4)));
typedef float f32x16 __attribute__((ext_vector_type(16)));

namespace {
constexpr int BB   = 64;
constexpr int TT   = 1002;
constexpr int DD   = 8;
constexpr int HH   = 64;
constexpr int LAGS = 2;
constexpr int NW   = TT - LAGS;      // 1000
constexpr int FIN  = LAGS * DD + 1;  // 17
constexpr int NTOT = BB * NW;        // 64000
constexpr int GXB  = 16;             // x-blocks; 2 waves/block; 32 windows/wave
constexpr int NSTR = 32;             // strips per (b,d)

constexpr int RES_OFF = 0;
constexpr int LOG_OFF = NTOT * DD;
constexpr int HJ_OFF  = LOG_OFF + BB;

// A-fragment pack for 32x32x16 MFMA (f16 units).
// Frag layout [mt][kc][lane 64][8]: m = 32*mt + (lane&31),
// k = kc*16 + (lane>>5)*8 + j.
constexpr int SZ_A0F = 2 * 2 * 64 * 8;   // M64 K32 (pad f>=17 -> 0)
constexpr int SZ_AH  = 2 * 4 * 64 * 8;   // M64 K64
constexpr int SZ_A0T = 1 * 4 * 64 * 8;   // M32 K64 (pad m>=17 -> 0)
constexpr int OA0F = 0;
constexpr int OA1F = OA0F + DD * SZ_A0F;
constexpr int OA2F = OA1F + DD * SZ_AH;
constexpr int OA2T = OA2F + DD * SZ_AH;
constexpr int OA1T = OA2T + DD * SZ_AH;
constexpr int OA0T = OA1T + DD * SZ_AH;
constexpr int WTOT = OA0T + DD * SZ_A0T;  // 163840 f16 = 320 KB

// LDS: per wave 3 regions (WORK | H0 | H1) x 32 rows x 128 B = 12 KB
constexpr int REG_H0   = 4096;
constexpr int REG_H1   = 8192;
constexpr int WV_STRIDE = 12288;
}

__device__ __forceinline__ unsigned int pku(float a, float b) {
    return __builtin_bit_cast(unsigned int, __builtin_amdgcn_cvt_pkrtz(a, b));
}
__device__ __forceinline__ h2t pmax(h2t a, h2t b) {
#if __has_builtin(__builtin_elementwise_max)
    return __builtin_elementwise_max(a, b);   // v_pk_max_f16
#else
    h2t r; r[0] = a[0] > b[0] ? a[0] : b[0]; r[1] = a[1] > b[1] ? a[1] : b[1];
    return r;
#endif
}
__device__ __forceinline__ float fdot2(h2t a, h2t b, float c) {
#if __has_builtin(__builtin_amdgcn_fdot2)
    return __builtin_amdgcn_fdot2(a, b, c, false);
#else
    return c + (float)a[0] * (float)b[0] + (float)a[1] * (float)b[1];
#endif
}

// Prepack weights into 32x32x16 per-lane A-fragments.
__global__ void setup_weights(const float* __restrict__ W0, const float* __restrict__ W1,
                              const float* __restrict__ W2, _Float16* __restrict__ wsp)
{
    for (int i = blockIdx.x * blockDim.x + threadIdx.x; i < WTOT;
         i += gridDim.x * blockDim.x) {
        float val;
        if (i < OA1F) {          // A0F: A[m=h][k=f], kc_cnt=2, K pad 17->32
            int j = i - OA0F, d = j / SZ_A0F, r = j % SZ_A0F;
            int mt = r / 1024, r2 = r % 1024, kc = r2 / 512, r3 = r2 % 512;
            int lane = r3 / 8, jj = r3 % 8;
            int m = 32 * mt + (lane & 31), k = kc * 16 + (lane >> 5) * 8 + jj;
            val = (k < FIN) ? W0[((size_t)d * HH + m) * FIN + k] : 0.0f;
        } else if (i < OA2F) {   // A1F
            int j = i - OA1F, d = j / SZ_AH, r = j % SZ_AH;
            int mt = r / 2048, r2 = r % 2048, kc = r2 / 512, r3 = r2 % 512;
            int lane = r3 / 8, jj = r3 % 8;
            int m = 32 * mt + (lane & 31), k = kc * 16 + (lane >> 5) * 8 + jj;
            val = W1[((size_t)d * HH + m) * HH + k];
        } else if (i < OA2T) {   // A2F
            int j = i - OA2F, d = j / SZ_AH, r = j % SZ_AH;
            int mt = r / 2048, r2 = r % 2048, kc = r2 / 512, r3 = r2 % 512;
            int lane = r3 / 8, jj = r3 % 8;
            int m = 32 * mt + (lane & 31), k = kc * 16 + (lane >> 5) * 8 + jj;
            val = W2[((size_t)d * HH + m) * HH + k];
        } else if (i < OA1T) {   // A2T: A[m=h'][k=g] = W2[d,k,m]
            int j = i - OA2T, d = j / SZ_AH, r = j % SZ_AH;
            int mt = r / 2048, r2 = r % 2048, kc = r2 / 512, r3 = r2 % 512;
            int lane = r3 / 8, jj = r3 % 8;
            int m = 32 * mt + (lane & 31), k = kc * 16 + (lane >> 5) * 8 + jj;
            val = W2[((size_t)d * HH + k) * HH + m];
        } else if (i < OA0T) {   // A1T: A[m=h][k=h'] = W1[d,k,m]
            int j = i - OA1T, d = j / SZ_AH, r = j % SZ_AH;
            int mt = r / 2048, r2 = r % 2048, kc = r2 / 512, r3 = r2 % 512;
            int lane = r3 / 8, jj = r3 % 8;
            int m = 32 * mt + (lane & 31), k = kc * 16 + (lane >> 5) * 8 + jj;
            val = W1[((size_t)d * HH + k) * HH + m];
        } else {                 // A0T: A[m=f][k=h] = W0[d,k,m], M pad 17->32
            int j = i - OA0T, d = j / SZ_A0T, r = j % SZ_A0T;
            int kc = r / 512, r3 = r % 512;
            int lane = r3 / 8, jj = r3 % 8;
            int m = lane & 31, k = kc * 16 + (lane >> 5) * 8 + jj;
            val = (m < FIN) ? W0[((size_t)d * HH + k) * FIN + m] : 0.0f;
        }
        wsp[i] = (_Float16)val;
    }
}

// Round-13: 32x32x16 MFMA, 32 windows/wave (waves halved to 16384) to
// amortize the per-stage stall chain that six 16-window structures all hit
// (73-84 us plateau, no pipe >50%). Wave-private 12KB LDS (WORK|H0|H1);
// barrier-free; round-12 minimal-VALU epilogues (pkrtz/pk_max/sign-bfi).
// Live set ~55-60 VGPR -> fits the allocator's observed 64-VGPR preference.
__global__ __launch_bounds__(128) void fused_mlp(
    const float* __restrict__ x,
    const float* __restrict__ b0, const float* __restrict__ a0,
    const float* __restrict__ b1, const float* __restrict__ a1,
    const float* __restrict__ b2, const float* __restrict__ a2,
    const float* __restrict__ W3, const float* __restrict__ b3,
    const _Float16* __restrict__ wsp,
    float* __restrict__ out, float* __restrict__ partials)
{
    const int b   = blockIdx.y;
    const int d   = blockIdx.z;
    const int tid = threadIdx.x;
    const int wv  = __builtin_amdgcn_readfirstlane(tid >> 6);  // 0..1
    const int t   = tid & 63;
    const int col = t & 31;          // window within strip (= C/D col, B n)
    const int hi2 = t >> 5;          // k-group / row-group selector
    const int strip = blockIdx.x * 2 + wv;
    const int n   = strip * 32 + col;
    const bool nv = (n < NW);

    __shared__ __align__(16) unsigned char Xs[2 * WV_STRIDE];  // 24 KB
    unsigned char* Xw = Xs + wv * WV_STRIDE;

    const int swz   = (col & 7) << 4;
    const int rbase = col * 128;
    // B-frag read addrs (WORK-relative): k = kc*16 + hi2*8 + j -> byte kc*32+hi2*16
    int rd[4];
    #pragma unroll
    for (int kc = 0; kc < 4; ++kc)
        rd[kc] = rbase + ((kc * 32 + hi2 * 16) ^ swz);

    // ---- stage inputs into WORK rows (lanes hi2==0; row = col) ----
    if (hi2 == 0) {
        const int w = min(strip * 32 + col, NW - 1);
        const float* xr = x + ((size_t)b * TT + w) * DD;
        f32x4 x0 = *(const f32x4*)(xr + 0);
        f32x4 x1 = *(const f32x4*)(xr + 4);
        f32x4 x2 = *(const f32x4*)(xr + 8);
        f32x4 x3 = *(const f32x4*)(xr + 12);
        float xl = xr[2 * DD + d];
        uint4 q0, q1, qz, zz;
        q0.x = pku(x0[0], x0[1]); q0.y = pku(x0[2], x0[3]);
        q0.z = pku(x1[0], x1[1]); q0.w = pku(x1[2], x1[3]);
        q1.x = pku(x2[0], x2[1]); q1.y = pku(x2[2], x2[3]);
        q1.z = pku(x3[0], x3[1]); q1.w = pku(x3[2], x3[3]);
        qz.x = pku(xl, 0.f); qz.y = 0u; qz.z = 0u; qz.w = 0u;
        zz.x = 0u; zz.y = 0u; zz.z = 0u; zz.w = 0u;
        *(uint4*)&Xw[rbase + (0  ^ swz)] = q0;   // k 0..7
        *(uint4*)&Xw[rbase + (16 ^ swz)] = q1;   // k 8..15
        *(uint4*)&Xw[rbase + (32 ^ swz)] = qz;   // k 16..23 (xl + 0)
        *(uint4*)&Xw[rbase + (48 ^ swz)] = zz;   // k 24..31 (pad)
    }
    // no fence: same-wave DS ordering; compiler inserts lgkmcnt waits

    const float A0f = a0[d], A1f = a1[d], A2f = a2[d];
    const h2t apk0 = __builtin_bit_cast(h2t, pku(A0f, A0f));
    const h2t apk1 = __builtin_bit_cast(h2t, pku(A1f, A1f));
    const h2t apk2 = __builtin_bit_cast(h2t, pku(A2f, A2f));

    // C tiles: col = col, row h = 32*mt + (reg&3) + 8*(reg>>2) + 4*hi2
    f32x16 C[2];

    auto zeroC = [&]() {
        #pragma unroll
        for (int mt = 0; mt < 2; ++mt)
            #pragma unroll
            for (int r = 0; r < 16; ++r) C[mt][r] = 0.0f;
    };
    auto biasInit = [&](const float* bp) {
        #pragma unroll
        for (int mt = 0; mt < 2; ++mt)
            #pragma unroll
            for (int g = 0; g < 4; ++g) {
                f32x4 bb = *(const f32x4*)(bp + 32 * mt + 8 * g + 4 * hi2);
                C[mt][4 * g + 0] = bb[0]; C[mt][4 * g + 1] = bb[1];
                C[mt][4 * g + 2] = bb[2]; C[mt][4 * g + 3] = bb[3];
            }
    };
    // K=64 GEMM, B from region `regoff` of WORK-space rows
    auto gemmK64 = [&](const _Float16* apk, int regoff) {
        #pragma unroll
        for (int kc = 0; kc < 4; ++kc) {
            half8 Bv = *(const half8*)&Xw[rd[kc] + regoff];
            #pragma unroll
            for (int mt = 0; mt < 2; ++mt) {
                half8 a = *(const half8*)(apk + (size_t)((mt * 4 + kc) * 64 + t) * 8);
                C[mt] = __builtin_amdgcn_mfma_f32_32x32x16_f16(a, Bv, C[mt], 0, 0, 0);
            }
        }
    };
    // write byte offset for (mt,g): h = 32mt+8g+4hi2 -> byte 64mt+16g+8hi2
    auto wroff = [&](int mt, int g) {
        return rbase + (((64 * mt + 16 * g) ^ swz) + 8 * hi2);
    };
    // forward: pack -> packed PReLU -> store to region
    auto preluStore = [&](h2t ap, int regoff) {
        #pragma unroll
        for (int mt = 0; mt < 2; ++mt)
            #pragma unroll
            for (int g = 0; g < 4; ++g) {
                unsigned lo_ = pku(C[mt][4 * g + 0], C[mt][4 * g + 1]);
                unsigned hi_ = pku(C[mt][4 * g + 2], C[mt][4 * g + 3]);
                h2t hl = __builtin_bit_cast(h2t, lo_);
                h2t hh = __builtin_bit_cast(h2t, hi_);
                hl = pmax(hl, hl * ap);
                hh = pmax(hh, hh * ap);
                uint2 p;
                p.x = __builtin_bit_cast(unsigned int, hl);
                p.y = __builtin_bit_cast(unsigned int, hh);
                *(uint2*)&Xw[wroff(mt, g) + regoff] = p;
            }
    };
    // backward: v' = v * d, d from sign of h' read from `hregoff`; store WORK
    auto dApplyStore = [&](h2t ap, int hregoff) {
        #pragma unroll
        for (int mt = 0; mt < 2; ++mt)
            #pragma unroll
            for (int g = 0; g < 4; ++g) {
                const int off = wroff(mt, g);
                uint2 hr = *(const uint2*)&Xw[off + hregoff];
                unsigned vx = pku(C[mt][4 * g + 0], C[mt][4 * g + 1]);
                unsigned vy = pku(C[mt][4 * g + 2], C[mt][4 * g + 3]);
                unsigned avx = __builtin_bit_cast(unsigned int,
                                   __builtin_bit_cast(h2t, vx) * ap);
                unsigned avy = __builtin_bit_cast(unsigned int,
                                   __builtin_bit_cast(h2t, vy) * ap);
                unsigned mx = ((hr.x & 0x80008000u) >> 15) * 0xFFFFu;
                unsigned my = ((hr.y & 0x80008000u) >> 15) * 0xFFFFu;
                uint2 p;
                p.x = (mx & avx) | (~mx & vx);
                p.y = (my & avy) | (~my & vy);
                *(uint2*)&Xw[off] = p;
            }
    };

    // ================= forward =================
    // L0: K=32 (kc 0..1)
    {
        const _Float16* apk = wsp + OA0F + (size_t)d * SZ_A0F;
        biasInit(b0 + d * HH);
        #pragma unroll
        for (int kc = 0; kc < 2; ++kc) {
            half8 Bv = *(const half8*)&Xw[rd[kc]];
            #pragma unroll
            for (int mt = 0; mt < 2; ++mt) {
                half8 a = *(const half8*)(apk + (size_t)((mt * 2 + kc) * 64 + t) * 8);
                C[mt] = __builtin_amdgcn_mfma_f32_32x32x16_f16(a, Bv, C[mt], 0, 0, 0);
            }
        }
    }
    preluStore(apk0, REG_H0);

    biasInit(b1 + d * HH);
    gemmK64(wsp + OA1F + (size_t)d * SZ_AH, REG_H0);
    preluStore(apk1, REG_H1);

    biasInit(b2 + d * HH);
    gemmK64(wsp + OA2F + (size_t)d * SZ_AH, REG_H1);

    // ---- h2 packed + residual dot + v2 init (no LDS round trip for d2) ----
    {
        uint2 h2p[2][4], w3p[2][4];
        float s = 0.0f;
        #pragma unroll
        for (int mt = 0; mt < 2; ++mt)
            #pragma unroll
            for (int g = 0; g < 4; ++g) {
                f32x4 w = *(const f32x4*)(W3 + d * HH + 32 * mt + 8 * g + 4 * hi2);
                w3p[mt][g].x = pku(w[0], w[1]);
                w3p[mt][g].y = pku(w[2], w[3]);
                unsigned lo_ = pku(C[mt][4 * g + 0], C[mt][4 * g + 1]);
                unsigned hi_ = pku(C[mt][4 * g + 2], C[mt][4 * g + 3]);
                h2t hl = __builtin_bit_cast(h2t, lo_);
                h2t hh = __builtin_bit_cast(h2t, hi_);
                hl = pmax(hl, hl * apk2);
                hh = pmax(hh, hh * apk2);
                h2p[mt][g].x = __builtin_bit_cast(unsigned int, hl);
                h2p[mt][g].y = __builtin_bit_cast(unsigned int, hh);
                s = fdot2(hl, __builtin_bit_cast(h2t, w3p[mt][g].x), s);
                s = fdot2(hh, __builtin_bit_cast(h2t, w3p[mt][g].y), s);
            }
        s += __shfl_xor(s, 32);   // combine the two h-halves (hi2 0/1)
        if (hi2 == 0 && nv)
            out[RES_OFF + ((size_t)b * NW + n) * DD + d] = s + b3[d];

        // v2 = w3 * d2 (d2 from h2 sign) -> WORK
        #pragma unroll
        for (int mt = 0; mt < 2; ++mt)
            #pragma unroll
            for (int g = 0; g < 4; ++g) {
                unsigned wax = __builtin_bit_cast(unsigned int,
                                   __builtin_bit_cast(h2t, w3p[mt][g].x) * apk2);
                unsigned way = __builtin_bit_cast(unsigned int,
                                   __builtin_bit_cast(h2t, w3p[mt][g].y) * apk2);
                unsigned mx = ((h2p[mt][g].x & 0x80008000u) >> 15) * 0xFFFFu;
                unsigned my = ((h2p[mt][g].y & 0x80008000u) >> 15) * 0xFFFFu;
                uint2 p;
                p.x = (mx & wax) | (~mx & w3p[mt][g].x);
                p.y = (my & way) | (~my & w3p[mt][g].y);
                *(uint2*)&Xw[wroff(mt, g)] = p;
            }
    }

    // ================= backward =================
    zeroC();
    gemmK64(wsp + OA2T + (size_t)d * SZ_AH, 0);
    dApplyStore(apk1, REG_H1);

    zeroC();
    gemmK64(wsp + OA1T + (size_t)d * SZ_AH, 0);
    dApplyStore(apk0, REG_H0);

    // G = W0T @ v0 : single M=32 tile; f = (reg&3) + 8*(reg>>2) + 4*hi2
    f32x16 G;
    {
        #pragma unroll
        for (int r = 0; r < 16; ++r) G[r] = 0.0f;
        const _Float16* apk = wsp + OA0T + (size_t)d * SZ_A0T;
        #pragma unroll
        for (int kc = 0; kc < 4; ++kc) {
            half8 Bv = *(const half8*)&Xw[rd[kc]];
            half8 a = *(const half8*)(apk + (size_t)(kc * 64 + t) * 8);
            G = __builtin_amdgcn_mfma_f32_32x32x16_f16(a, Bv, G, 0, 0, 0);
        }
    }

    // hist_jac: groups g=0,1 cover f 0..15 (f_base = 8g + 4*hi2)
    if (nv) {
        #pragma unroll
        for (int g = 0; g < 2; ++g) {
            f32x4 v;
            v[0] = G[4 * g + 0]; v[1] = G[4 * g + 1];
            v[2] = G[4 * g + 2]; v[3] = G[4 * g + 3];
            *(f32x4*)(out + HJ_OFF + ((size_t)d * NTOT + (size_t)b * NW + n) * 16
                      + 8 * g + 4 * hi2) = v;
        }
    }

    // log|g[16]|: f=16 -> reg 8, hi2==0 lanes
    {
        float ld = (hi2 == 0 && nv) ? __logf(fabsf(G[8])) : 0.0f;
        #pragma unroll
        for (int off = 32; off > 0; off >>= 1) ld += __shfl_down(ld, off);
        if (t == 0) partials[(b * DD + d) * NSTR + strip] = ld;
    }
}

__global__ void reduce_log(const float* __restrict__ partials, float* __restrict__ out)
{
    const int b = blockIdx.x;     // BB blocks x 64 threads
    const int t = threadIdx.x;
    float s = 0.0f;
    #pragma unroll
    for (int i = 0; i < 4; ++i) s += partials[b * (DD * NSTR) + t * 4 + i];
    #pragma unroll
    for (int off = 32; off > 0; off >>= 1) s += __shfl_down(s, off);
    if (t == 0) out[LOG_OFF + b] = s;
}

extern "C" void kernel_launch(void* const* d_in, const int* in_sizes, int n_in,
                              void* d_out, int out_size, void* d_ws, size_t ws_size,
                              hipStream_t stream)
{
    const float* x  = (const float*)d_in[0];
    const float* W0 = (const float*)d_in[1];
    const float* b0 = (const float*)d_in[2];
    const float* a0 = (const float*)d_in[3];
    const float* W1 = (const float*)d_in[4];
    const float* b1 = (const float*)d_in[5];
    const float* a1 = (const float*)d_in[6];
    const float* W2 = (const float*)d_in[7];
    const float* b2 = (const float*)d_in[8];
    const float* a2 = (const float*)d_in[9];
    const float* W3 = (const float*)d_in[10];
    const float* b3 = (const float*)d_in[11];

    float*     out      = (float*)d_out;
    _Float16*  wsp      = (_Float16*)d_ws;
    float*     partials = (float*)((char*)d_ws + (size_t)WTOT * 2);  // 16384 floats

    setup_weights<<<160, 1024, 0, stream>>>(W0, W1, W2, wsp);

    dim3 grid(GXB, BB, DD);   // 16 x 64 x 8 = 8192 blocks x 2 waves (32 win/wave)
    fused_mlp<<<grid, 128, 0, stream>>>(x, b0, a0, b1, a1, b2, a2, W3, b3,
                                        wsp, out, partials);
    reduce_log<<<BB, 64, 0, stream>>>(partials, out);
}